// Round 4
// baseline (732.745 us; speedup 1.0000x reference)
//
#include <hip/hip_runtime.h>
#include <math.h>

// GatedAttention B=32, C=512, T=1024, fp32 in/out. Split-bf16 (hi/lo) MFMA.
// R4 restructure: stacked qkv gemm (M=1536, gates in native [d][t] layout),
// 128x64 / 64x64 tiles for 3-4 blocks/CU co-residency, gvT fp32 transpose
// eliminated (replaced by small bf16 vT->V transpose).
// Pipeline per chunk (bc batches):
//   T0: x[b,c,t] -> xT hi/lo [t][c]
//   G1: [q;k;vT][d,t] = gate[d,t]*(W_stk . xT + b)   M=1536,N=1024,K=512
//   T1: vT[d][t] hi/lo -> V[t][d] hi/lo
//   G2: E[c,d] = SCALE * qT[c,:].kT[d,:]             M=512,N=512,K=1024
//   S:  row softmax, split -> attn hi/lo
//   G3: out[c,t] = attn[c,:].V[:,d]^T                M=512,N=1024,K=512

#define B_ 32
#define C_ 512
#define T_ 1024
#define TC_ ((size_t)524288)   // T*C
#define CC_ ((size_t)262144)   // C*C
#define SCALE_ 0.04419417382415922f

typedef short bf16x8 __attribute__((ext_vector_type(8)));
typedef float f32x4 __attribute__((ext_vector_type(4)));
typedef unsigned short u16;

__device__ __forceinline__ u16 f2b(float f) {
    unsigned int u = __float_as_uint(f);
    u += 0x7fff + ((u >> 16) & 1);
    return (u16)(u >> 16);
}
__device__ __forceinline__ float b2f(u16 h) {
    return __uint_as_float(((unsigned int)h) << 16);
}

#define GLDS(gp, lp) __builtin_amdgcn_global_load_lds( \
    (const __attribute__((address_space(1))) unsigned int*)(const void*)(gp), \
    (__attribute__((address_space(3))) unsigned int*)(void*)(lp), 16, 0, 0)

// ---- shared NT-gemm core: TM x 64 tile, BK=32, 4 waves as 2x2, 3-pass split-bf16
// A[m][k], B[n][k], both row-stride kk, k-contiguous. acc[AM][2] per wave.
template<int TM>
__device__ __forceinline__ void gemm_core(
    const u16* __restrict__ Ah, const u16* __restrict__ Al,
    const u16* __restrict__ Bh, const u16* __restrict__ Bl,
    int m0, int n0, int kk, f32x4 (*acc)[2])
{
    constexpr int AM  = TM / 32;             // a-frags per wave
    constexpr int NI  = (TM / 16 + 4) * 2;   // GLDS issues per K-step
    constexpr int NPI = NI / 4;              // per wave
    __shared__ __attribute__((aligned(16))) u16 sAh[TM * 32];
    __shared__ __attribute__((aligned(16))) u16 sAl[TM * 32];
    __shared__ __attribute__((aligned(16))) u16 sBh[64 * 32];
    __shared__ __attribute__((aligned(16))) u16 sBl[64 * 32];

    const int tid  = threadIdx.x;
    const int lane = tid & 63;
    const int wave = tid >> 6;
    const int lr = lane >> 2;                // staging row within 16-row group
    const int lk = (lane & 3) * 8;           // staging k-chunk (shorts)
    const int wm = (wave & 1) * (TM / 2);
    const int wn = (wave >> 1) * 32;
    const int fr = lane & 15;
    const int fk = (lane >> 4) * 8;

    const u16* gb[NPI];
    u16* lb[NPI];
    #pragma unroll
    for (int j = 0; j < NPI; ++j) {
        int i = wave + j * 4;
        int plane = i & 1, p = i >> 1;
        if (p < TM / 16) {
            gb[j] = (plane ? Al : Ah) + (size_t)(m0 + p * 16 + lr) * kk + lk;
            lb[j] = (plane ? sAl : sAh) + p * 512;
        } else {
            int q = p - TM / 16;
            gb[j] = (plane ? Bl : Bh) + (size_t)(n0 + q * 16 + lr) * kk + lk;
            lb[j] = (plane ? sBl : sBh) + q * 512;
        }
    }

    for (int k0 = 0; k0 < kk; k0 += 32) {
        #pragma unroll
        for (int j = 0; j < NPI; ++j) GLDS(gb[j] + k0, lb[j]);
        __syncthreads();

        bf16x8 aH[AM], aL[AM], bH[2], bL[2];
        #pragma unroll
        for (int i = 0; i < AM; ++i) {
            int off = (wm + i * 16 + fr) * 32 + fk;
            aH[i] = *(const bf16x8*)(const void*)&sAh[off];
            aL[i] = *(const bf16x8*)(const void*)&sAl[off];
        }
        #pragma unroll
        for (int j = 0; j < 2; ++j) {
            int off = (wn + j * 16 + fr) * 32 + fk;
            bH[j] = *(const bf16x8*)(const void*)&sBh[off];
            bL[j] = *(const bf16x8*)(const void*)&sBl[off];
        }
        #pragma unroll
        for (int mi = 0; mi < AM; ++mi)
            #pragma unroll
            for (int ni = 0; ni < 2; ++ni) {
                acc[mi][ni] = __builtin_amdgcn_mfma_f32_16x16x32_bf16(aL[mi], bH[ni], acc[mi][ni], 0, 0, 0);
                acc[mi][ni] = __builtin_amdgcn_mfma_f32_16x16x32_bf16(aH[mi], bL[ni], acc[mi][ni], 0, 0, 0);
                acc[mi][ni] = __builtin_amdgcn_mfma_f32_16x16x32_bf16(aH[mi], bH[ni], acc[mi][ni], 0, 0, 0);
            }
        __syncthreads();
    }
}

// ---- G1: stacked qkv. A = W_stk [1536][512], B = xT[bz] [1024][512].
__global__ __launch_bounds__(256, 3) void gemm_qkv(
    const u16* __restrict__ Wh, const u16* __restrict__ Wl,
    const u16* __restrict__ xTh, const u16* __restrict__ xTl,
    const float* __restrict__ gq, const float* __restrict__ gk, const float* __restrict__ gv,
    const float* __restrict__ bq, const float* __restrict__ bk, const float* __restrict__ bv,
    u16* __restrict__ Qh, u16* __restrict__ Ql,
    u16* __restrict__ Kh, u16* __restrict__ Kl,
    u16* __restrict__ Th, u16* __restrict__ Tl)
{
    const int bz = blockIdx.z;
    const int m0 = blockIdx.y * 128;
    const int n0 = blockIdx.x * 64;

    f32x4 acc[4][2] = {};
    gemm_core<128>(Wh, Wl, xTh + (size_t)bz * TC_, xTl + (size_t)bz * TC_,
                   m0, n0, 512, acc);

    const int seg = m0 >> 9;   // block-uniform: 0=q, 1=k, 2=v
    const float* gate = (seg == 0 ? gq : seg == 1 ? gk : gv) + (size_t)bz * TC_;
    const float* bias = (seg == 0 ? bq : seg == 1 ? bk : bv);
    u16* oh = (seg == 0 ? Qh : seg == 1 ? Kh : Th) + (size_t)bz * TC_;
    u16* ol = (seg == 0 ? Ql : seg == 1 ? Kl : Tl) + (size_t)bz * TC_;

    const int lane = threadIdx.x & 63, wave = threadIdx.x >> 6;
    const int wm = (wave & 1) * 64, wn = (wave >> 1) * 32, fr = lane & 15;
    #pragma unroll
    for (int mi = 0; mi < 4; ++mi)
        #pragma unroll
        for (int r = 0; r < 4; ++r) {
            int m = (m0 & 511) + wm + mi * 16 + ((lane >> 4) << 2) + r;
            float bb = bias[m];
            #pragma unroll
            for (int ni = 0; ni < 2; ++ni) {
                int n = n0 + wn + ni * 16 + fr;
                size_t idx = (size_t)m * T_ + n;
                float val = gate[idx] * (acc[mi][ni][r] + bb);
                u16 h = f2b(val);
                oh[idx] = h;
                ol[idx] = f2b(val - b2f(h));
            }
        }
}

// ---- G2: E = SCALE * Q.K^T (both [d][t], K-dim = t = 1024)
__global__ __launch_bounds__(256, 4) void gemm_e(
    const u16* __restrict__ Qh, const u16* __restrict__ Ql,
    const u16* __restrict__ Kh, const u16* __restrict__ Kl,
    float* __restrict__ E)
{
    const int bz = blockIdx.z;
    const int m0 = blockIdx.y * 64;
    const int n0 = blockIdx.x * 64;

    f32x4 acc[2][2] = {};
    gemm_core<64>(Qh + (size_t)bz * TC_, Ql + (size_t)bz * TC_,
                  Kh + (size_t)bz * TC_, Kl + (size_t)bz * TC_,
                  m0, n0, 1024, acc);

    float* Eb = E + (size_t)bz * CC_;
    const int lane = threadIdx.x & 63, wave = threadIdx.x >> 6;
    const int wm = (wave & 1) * 32, wn = (wave >> 1) * 32, fr = lane & 15;
    #pragma unroll
    for (int mi = 0; mi < 2; ++mi)
        #pragma unroll
        for (int r = 0; r < 4; ++r) {
            int m = m0 + wm + mi * 16 + ((lane >> 4) << 2) + r;
            #pragma unroll
            for (int ni = 0; ni < 2; ++ni) {
                int n = n0 + wn + ni * 16 + fr;
                Eb[(size_t)m * C_ + n] = acc[mi][ni][r] * SCALE_;
            }
        }
}

// ---- G3: out = attn . V^T  (attn [c][d], V [t][d]) -> out[c][t] fp32
__global__ __launch_bounds__(256, 4) void gemm_out(
    const u16* __restrict__ Ah, const u16* __restrict__ Al,
    const u16* __restrict__ Vh, const u16* __restrict__ Vl,
    float* __restrict__ out)
{
    const int bz = blockIdx.z;
    const int m0 = blockIdx.y * 64;
    const int n0 = blockIdx.x * 64;

    f32x4 acc[2][2] = {};
    gemm_core<64>(Ah + (size_t)bz * CC_, Al + (size_t)bz * CC_,
                  Vh + (size_t)bz * TC_, Vl + (size_t)bz * TC_,
                  m0, n0, 512, acc);

    float* ob = out + (size_t)bz * TC_;
    const int lane = threadIdx.x & 63, wave = threadIdx.x >> 6;
    const int wm = (wave & 1) * 32, wn = (wave >> 1) * 32, fr = lane & 15;
    #pragma unroll
    for (int mi = 0; mi < 2; ++mi)
        #pragma unroll
        for (int r = 0; r < 4; ++r) {
            int m = m0 + wm + mi * 16 + ((lane >> 4) << 2) + r;
            #pragma unroll
            for (int ni = 0; ni < 2; ++ni) {
                int n = n0 + wn + ni * 16 + fr;
                ob[(size_t)m * T_ + n] = acc[mi][ni][r];
            }
        }
}

// ---- T0: x[c][t] fp32 -> xT[t][c] bf16 hi/lo
__global__ __launch_bounds__(256) void transpose_split(
    const float* __restrict__ x, u16* __restrict__ xThi, u16* __restrict__ xTlo)
{
    __shared__ float s[64][65];
    const int bz = blockIdx.z;
    const int t0 = blockIdx.x * 64, c0 = blockIdx.y * 64;
    const float* src = x + (size_t)bz * TC_;
    const int col = threadIdx.x & 63, rb = threadIdx.x >> 6;

    #pragma unroll
    for (int i = 0; i < 64; i += 4)
        s[i + rb][col] = src[(size_t)(c0 + i + rb) * T_ + t0 + col];
    __syncthreads();

    const size_t ob = (size_t)bz * TC_;
    #pragma unroll
    for (int i = 0; i < 64; i += 4) {
        int tr = i + rb;
        float v = s[col][tr];
        size_t o = ob + (size_t)(t0 + tr) * C_ + c0 + col;
        u16 h = f2b(v);
        xThi[o] = h;
        xTlo[o] = f2b(v - b2f(h));
    }
}

// ---- T1: vT[d][t] -> V[t][d], bf16 planes (z = plane*bc + bz)
__global__ __launch_bounds__(256) void transpose_bf(
    const u16* __restrict__ s0, const u16* __restrict__ s1,
    u16* __restrict__ d0p, u16* __restrict__ d1p, int bc)
{
    __shared__ u16 s[64][65];
    const int z = blockIdx.z;
    const int plane = z >= bc ? 1 : 0;
    const int bz = z - plane * bc;
    const u16* src = (plane ? s1 : s0) + (size_t)bz * TC_;
    u16* dst = (plane ? d1p : d0p) + (size_t)bz * TC_;
    const int d0 = blockIdx.y * 64, t0 = blockIdx.x * 64;
    const int tp = threadIdx.x & 31, rr = threadIdx.x >> 5;

    #pragma unroll
    for (int i = 0; i < 64; i += 8) {
        int d = i + rr;
        ushort2 v = *(const ushort2*)(const void*)&src[(size_t)(d0 + d) * T_ + t0 + tp * 2];
        s[tp * 2][d] = v.x;
        s[tp * 2 + 1][d] = v.y;
    }
    __syncthreads();
    #pragma unroll
    for (int i = 0; i < 64; i += 8) {
        int t = i + rr;
        ushort2 v;
        v.x = s[t][tp * 2];
        v.y = s[t][tp * 2 + 1];
        *(ushort2*)(void*)&dst[(size_t)(t0 + t) * C_ + d0 + tp * 2] = v;
    }
}

// ---- W split: stacked [Wq;Wk;Wv] -> hi/lo bf16 [1536][512]
__global__ __launch_bounds__(256) void split_w(
    const float* __restrict__ Wq, const float* __restrict__ Wk,
    const float* __restrict__ Wv, u16* __restrict__ hi, u16* __restrict__ lo)
{
    size_t i = (size_t)blockIdx.x * 256 + threadIdx.x;
    const float* src = i < CC_ ? Wq : (i < 2 * CC_ ? Wk : Wv);
    size_t off = i < CC_ ? i : (i < 2 * CC_ ? i - CC_ : i - 2 * CC_);
    float v = src[off];
    u16 h = f2b(v);
    hi[i] = h;
    lo[i] = f2b(v - b2f(h));
}

// ---- softmax over rows of 512, split-store attn hi/lo
__global__ __launch_bounds__(256) void softmax_split(
    const float* __restrict__ E, u16* __restrict__ Ahi, u16* __restrict__ Alo)
{
    const int row = blockIdx.x;
    const float* p = E + (size_t)row * C_;
    const int tid = threadIdx.x;

    float v0 = p[tid], v1 = p[tid + 256];
    float m = fmaxf(v0, v1);
    #pragma unroll
    for (int off = 32; off > 0; off >>= 1)
        m = fmaxf(m, __shfl_down(m, off, 64));

    __shared__ float sm[4];
    if ((tid & 63) == 0) sm[tid >> 6] = m;
    __syncthreads();
    float M = fmaxf(fmaxf(sm[0], sm[1]), fmaxf(sm[2], sm[3]));

    float e0 = expf(v0 - M), e1 = expf(v1 - M);
    float s = e0 + e1;
    #pragma unroll
    for (int off = 32; off > 0; off >>= 1)
        s += __shfl_down(s, off, 64);

    __shared__ float ss[4];
    if ((tid & 63) == 0) ss[tid >> 6] = s;
    __syncthreads();
    float inv = 1.0f / (ss[0] + ss[1] + ss[2] + ss[3]);

    float a0 = e0 * inv, a1 = e1 * inv;
    size_t o = (size_t)row * C_ + tid;
    u16 h0 = f2b(a0);
    Ahi[o] = h0;  Alo[o] = f2b(a0 - b2f(h0));
    u16 h1 = f2b(a1);
    Ahi[o + 256] = h1;  Alo[o + 256] = f2b(a1 - b2f(h1));
}

extern "C" void kernel_launch(void* const* d_in, const int* in_sizes, int n_in,
                              void* d_out, int out_size, void* d_ws, size_t ws_size,
                              hipStream_t stream) {
    const float* x  = (const float*)d_in[0];
    const float* gq = (const float*)d_in[1];
    const float* gk = (const float*)d_in[2];
    const float* gv = (const float*)d_in[3];
    const float* Wq = (const float*)d_in[4];
    const float* bq = (const float*)d_in[5];
    const float* Wk = (const float*)d_in[6];
    const float* bk = (const float*)d_in[7];
    const float* Wv = (const float*)d_in[8];
    const float* bv = (const float*)d_in[9];
    float* out = (float*)d_out;

    // per-batch ws: xT(2) Q(2) K(2) vT(2) V(2) E(1) attn(1) = 12 MB; W planes 3 MB
    const size_t wBytes = 2 * (3 * CC_) * 2;                        // 3 MB
    const size_t perBatch = 10 * TC_ * 2 + CC_ * 4 + 2 * CC_ * 2;   // 12 MB
    int bc = 1;
    for (int cand = B_; cand >= 1; cand >>= 1)
        if (wBytes + (size_t)cand * perBatch <= ws_size) { bc = cand; break; }

    char* p = (char*)d_ws;
    auto take = [&](size_t bytes) { char* r = p; p += bytes; return r; };
    u16* Wh  = (u16*)take(3 * CC_ * 2);
    u16* Wl  = (u16*)take(3 * CC_ * 2);
    u16* xTh = (u16*)take((size_t)bc * TC_ * 2);
    u16* xTl = (u16*)take((size_t)bc * TC_ * 2);
    u16* Qh  = (u16*)take((size_t)bc * TC_ * 2);
    u16* Ql  = (u16*)take((size_t)bc * TC_ * 2);
    u16* Kh  = (u16*)take((size_t)bc * TC_ * 2);
    u16* Kl  = (u16*)take((size_t)bc * TC_ * 2);
    u16* Th  = (u16*)take((size_t)bc * TC_ * 2);   // vT planes
    u16* Tl  = (u16*)take((size_t)bc * TC_ * 2);
    u16* Vh  = (u16*)take((size_t)bc * TC_ * 2);
    u16* Vl  = (u16*)take((size_t)bc * TC_ * 2);
    float* E = (float*)take((size_t)bc * CC_ * 4);
    u16* Ah  = (u16*)take((size_t)bc * CC_ * 2);
    u16* Al  = (u16*)take((size_t)bc * CC_ * 2);

    dim3 blk(256);
    split_w<<<(int)(3 * CC_ / 256), blk, 0, stream>>>(Wq, Wk, Wv, Wh, Wl);

    for (int b_off = 0; b_off < B_; b_off += bc) {
        transpose_split<<<dim3(16, 8, bc), blk, 0, stream>>>(
            x + (size_t)b_off * TC_, xTh, xTl);
        gemm_qkv<<<dim3(16, 12, bc), blk, 0, stream>>>(
            Wh, Wl, xTh, xTl,
            gq + (size_t)b_off * TC_, gk + (size_t)b_off * TC_, gv + (size_t)b_off * TC_,
            bq, bk, bv, Qh, Ql, Kh, Kl, Th, Tl);
        transpose_bf<<<dim3(16, 8, 2 * bc), blk, 0, stream>>>(Th, Tl, Vh, Vl, bc);
        gemm_e<<<dim3(8, 8, bc), blk, 0, stream>>>(Qh, Ql, Kh, Kl, E);
        softmax_split<<<dim3(bc * C_), blk, 0, stream>>>(E, Ah, Al);
        gemm_out<<<dim3(16, 8, bc), blk, 0, stream>>>(
            Ah, Al, Vh, Vl, out + (size_t)b_off * TC_);
    }
}